// Round 1
// baseline (17563.213 us; speedup 1.0000x reference)
//
#include <hip/hip_runtime.h>
#include <math.h>

// ---------------------------------------------------------------------------
// TextTransformer forward on MI355X — Round 1: correctness-first fp32.
// B=32 S=512 D=768 H=12 DH=64 FF=3072 L=4.
// GEMMs: 128x128x8 LDS-tiled SGEMM (8x8 micro, split 4+4 for bank-free reads).
// Attention: fused per (b,h,16-q-rows) block, scores row in LDS, exact softmax.
// ---------------------------------------------------------------------------

#define B_  32
#define S_  512
#define D_  768
#define H_  12
#define DH_ 64
#define FF_ 3072
#define L_  4

// ----------------------------- positional encoding -------------------------
__global__ void pe_kernel(float* __restrict__ pe) {
    int idx = blockIdx.x * 256 + threadIdx.x;
    if (idx >= S_ * D_) return;
    int s = idx / D_, j = idx % D_;
    double e = (2.0 * (double)(j >> 1)) / (double)D_;
    double denom = pow(10000.0, e);
    double ang = (double)s / denom;
    pe[idx] = (j & 1) ? (float)cos(ang) : (float)sin(ang);
}

// ----------------------------- embedding + PE ------------------------------
__global__ void embed_kernel(const int* __restrict__ tokens,
                             const float* __restrict__ emb,
                             const float* __restrict__ pe,
                             float* __restrict__ x) {
    int row = blockIdx.x;              // b*S + s
    int s = row & (S_ - 1);
    int tok = tokens[row];
    float scale = sqrtf((float)D_);
    for (int i = threadIdx.x; i < D_; i += 256) {
        x[(size_t)row * D_ + i] = emb[(size_t)tok * D_ + i] * scale + pe[s * D_ + i];
    }
}

// ----------------------------- tiled SGEMM + bias (+relu) ------------------
// C[M,N] = A[M,K] @ W[K,N] + bias[N]; act==1 -> relu. All dims %128 (K %8).
__global__ __launch_bounds__(256) void gemm_bias(
    const float* __restrict__ A, const float* __restrict__ W,
    const float* __restrict__ bias, float* __restrict__ C,
    int M, int N, int K, int act)
{
    __shared__ alignas(16) float sA[8][128];   // [k][m] transposed
    __shared__ alignas(16) float sB[8][128];   // [k][n]
    int t = threadIdx.x;
    int tx = t & 15, ty = t >> 4;
    int n0 = blockIdx.x * 128, m0 = blockIdx.y * 128;
    int a_m = t >> 1, a_k = (t & 1) * 4;       // A staging: 128 rows x 8 k
    int b_k = t >> 5, b_n = (t & 31) * 4;      // B staging: 8 k x 128 n
    const float* Ap = A + (size_t)(m0 + a_m) * K + a_k;

    float acc[8][8];
#pragma unroll
    for (int i = 0; i < 8; i++)
#pragma unroll
        for (int j = 0; j < 8; j++) acc[i][j] = 0.f;

    for (int k0 = 0; k0 < K; k0 += 8) {
        float4 av4 = *(const float4*)(Ap + k0);
        float4 bv4 = *(const float4*)(W + (size_t)(k0 + b_k) * N + n0 + b_n);
        __syncthreads();                        // prev iter compute done
        sA[a_k + 0][a_m] = av4.x;
        sA[a_k + 1][a_m] = av4.y;
        sA[a_k + 2][a_m] = av4.z;
        sA[a_k + 3][a_m] = av4.w;
        *(float4*)&sB[b_k][b_n] = bv4;
        __syncthreads();
#pragma unroll
        for (int kk = 0; kk < 8; kk++) {
            float4 a0 = *(float4*)&sA[kk][ty * 4];
            float4 a1 = *(float4*)&sA[kk][64 + ty * 4];
            float4 b0 = *(float4*)&sB[kk][tx * 4];
            float4 b1 = *(float4*)&sB[kk][64 + tx * 4];
            float ar[8] = {a0.x, a0.y, a0.z, a0.w, a1.x, a1.y, a1.z, a1.w};
            float br[8] = {b0.x, b0.y, b0.z, b0.w, b1.x, b1.y, b1.z, b1.w};
#pragma unroll
            for (int i = 0; i < 8; i++)
#pragma unroll
                for (int j = 0; j < 8; j++)
                    acc[i][j] += ar[i] * br[j];
        }
    }

#pragma unroll
    for (int hm = 0; hm < 2; hm++) {
#pragma unroll
        for (int i = 0; i < 4; i++) {
            int r = m0 + hm * 64 + ty * 4 + i;
#pragma unroll
            for (int hn = 0; hn < 2; hn++) {
                int c = n0 + hn * 64 + tx * 4;
                float4 o;
                o.x = acc[hm * 4 + i][hn * 4 + 0] + bias[c + 0];
                o.y = acc[hm * 4 + i][hn * 4 + 1] + bias[c + 1];
                o.z = acc[hm * 4 + i][hn * 4 + 2] + bias[c + 2];
                o.w = acc[hm * 4 + i][hn * 4 + 3] + bias[c + 3];
                if (act) {
                    o.x = fmaxf(o.x, 0.f); o.y = fmaxf(o.y, 0.f);
                    o.z = fmaxf(o.z, 0.f); o.w = fmaxf(o.w, 0.f);
                }
                *(float4*)&C[(size_t)r * N + c] = o;
            }
        }
    }
}

// ----------------------------- fused attention -----------------------------
// One block: (qt, h, b) -> 16 q-rows. Scores [16][512] in LDS, exact softmax.
#define TQ 16
__global__ __launch_bounds__(256) void attn_kernel(
    const float* __restrict__ q, const float* __restrict__ k,
    const float* __restrict__ v, float* __restrict__ av)
{
    __shared__ alignas(16) float sQ[TQ][68];
    __shared__ alignas(16) float sKV[64][68];
    __shared__ float sS[TQ][513];
    __shared__ float red[TQ][16];
    __shared__ float rowstat[TQ];
    int t = threadIdx.x;
    int qt = blockIdx.x, h = blockIdx.y, b = blockIdx.z;
    int tx = t & 15, ty = t >> 4;

    for (int i = t; i < TQ * DH_; i += 256) {
        int rr = i >> 6, d = i & 63;
        sQ[rr][d] = q[(size_t)(b * S_ + qt * TQ + rr) * D_ + h * DH_ + d];
    }
    // phase 1: S = Q K^T * scale
    int c = tx * 4;
    for (int kt = 0; kt < S_ / 64; kt++) {
        __syncthreads();
        for (int i = t; i < 64 * DH_; i += 256) {
            int rr = i >> 6, d = i & 63;
            sKV[rr][d] = k[(size_t)(b * S_ + kt * 64 + rr) * D_ + h * DH_ + d];
        }
        __syncthreads();
        float a0 = 0, a1 = 0, a2 = 0, a3 = 0;
#pragma unroll
        for (int d4 = 0; d4 < 16; d4++) {
            float4 q4 = *(float4*)&sQ[ty][d4 * 4];
            float4 k0 = *(float4*)&sKV[c + 0][d4 * 4];
            float4 k1 = *(float4*)&sKV[c + 1][d4 * 4];
            float4 k2 = *(float4*)&sKV[c + 2][d4 * 4];
            float4 k3 = *(float4*)&sKV[c + 3][d4 * 4];
            a0 += q4.x * k0.x + q4.y * k0.y + q4.z * k0.z + q4.w * k0.w;
            a1 += q4.x * k1.x + q4.y * k1.y + q4.z * k1.z + q4.w * k1.w;
            a2 += q4.x * k2.x + q4.y * k2.y + q4.z * k2.z + q4.w * k2.w;
            a3 += q4.x * k3.x + q4.y * k3.y + q4.z * k3.z + q4.w * k3.w;
        }
        sS[ty][kt * 64 + c + 0] = a0 * 0.125f;
        sS[ty][kt * 64 + c + 1] = a1 * 0.125f;
        sS[ty][kt * 64 + c + 2] = a2 * 0.125f;
        sS[ty][kt * 64 + c + 3] = a3 * 0.125f;
    }
    __syncthreads();
    // phase 2: softmax over 512 cols; 16 lanes per row, 32 cols each
    float mx = -1e30f;
    for (int m2 = 0; m2 < 32; m2++) mx = fmaxf(mx, sS[ty][tx + m2 * 16]);
    red[ty][tx] = mx;
    __syncthreads();
    if (tx == 0) {
        float mm = red[ty][0];
        for (int j2 = 1; j2 < 16; j2++) mm = fmaxf(mm, red[ty][j2]);
        rowstat[ty] = mm;
    }
    __syncthreads();
    float rm = rowstat[ty];
    float sum = 0.f;
    for (int m2 = 0; m2 < 32; m2++) {
        float e = __expf(sS[ty][tx + m2 * 16] - rm);
        sS[ty][tx + m2 * 16] = e;
        sum += e;
    }
    red[ty][tx] = sum;
    __syncthreads();
    if (tx == 0) {
        float ss = 0.f;
        for (int j2 = 0; j2 < 16; j2++) ss += red[ty][j2];
        rowstat[ty] = ss;
    }
    __syncthreads();
    float inv = 1.0f / rowstat[ty];
    for (int m2 = 0; m2 < 32; m2++) sS[ty][tx + m2 * 16] *= inv;
    // phase 3: O = P @ V
    float o0 = 0, o1 = 0, o2 = 0, o3 = 0;
    for (int kt = 0; kt < S_ / 64; kt++) {
        __syncthreads();
        for (int i = t; i < 64 * DH_; i += 256) {
            int rr = i >> 6, d = i & 63;
            sKV[rr][d] = v[(size_t)(b * S_ + kt * 64 + rr) * D_ + h * DH_ + d];
        }
        __syncthreads();
#pragma unroll 8
        for (int kk = 0; kk < 64; kk++) {
            float p = sS[ty][kt * 64 + kk];
            float4 v4 = *(float4*)&sKV[kk][tx * 4];
            o0 += p * v4.x; o1 += p * v4.y; o2 += p * v4.z; o3 += p * v4.w;
        }
    }
    size_t ob = (size_t)(b * S_ + qt * TQ + ty) * D_ + h * DH_ + tx * 4;
    av[ob + 0] = o0; av[ob + 1] = o1; av[ob + 2] = o2; av[ob + 3] = o3;
}

// ----------------------------- residual + layernorm (in-place on x) --------
__global__ __launch_bounds__(256) void add_ln(float* __restrict__ x,
    const float* __restrict__ r, const float* __restrict__ g,
    const float* __restrict__ bta)
{
    __shared__ float sred[256];
    int row = blockIdx.x, t = threadIdx.x;
    size_t base = (size_t)row * D_;
    float v0 = x[base + t]       + r[base + t];
    float v1 = x[base + t + 256] + r[base + t + 256];
    float v2 = x[base + t + 512] + r[base + t + 512];
    sred[t] = v0 + v1 + v2;
    __syncthreads();
    for (int o = 128; o > 0; o >>= 1) { if (t < o) sred[t] += sred[t + o]; __syncthreads(); }
    float mean = sred[0] * (1.0f / D_);
    __syncthreads();
    float d0 = v0 - mean, d1 = v1 - mean, d2 = v2 - mean;
    sred[t] = d0 * d0 + d1 * d1 + d2 * d2;
    __syncthreads();
    for (int o = 128; o > 0; o >>= 1) { if (t < o) sred[t] += sred[t + o]; __syncthreads(); }
    float rstd = rsqrtf(sred[0] * (1.0f / D_) + 1e-6f);
    x[base + t]       = g[t]       * d0 * rstd + bta[t];
    x[base + t + 256] = g[t + 256] * d1 * rstd + bta[t + 256];
    x[base + t + 512] = g[t + 512] * d2 * rstd + bta[t + 512];
}

// ----------------------------- mean pool over S ----------------------------
__global__ void pool_kernel(const float* __restrict__ x, float* __restrict__ pooled) {
    int idx = blockIdx.x * 256 + threadIdx.x;   // b*768 + d
    int b = idx / D_, d = idx % D_;
    float acc = 0.f;
    const float* p = x + (size_t)b * S_ * D_ + d;
    for (int s = 0; s < S_; s++) acc += p[(size_t)s * D_];
    pooled[idx] = acc * (1.0f / S_);
}

// ----------------------------- classifier head -----------------------------
__global__ void head_kernel(const float* __restrict__ pooled,
                            const float* __restrict__ wl,
                            const float* __restrict__ bl,
                            const float* __restrict__ wout,
                            const float* __restrict__ bout,
                            float* __restrict__ out)
{
    __shared__ float hb[32];
    int b = blockIdx.x, t = threadIdx.x;
    if (t < 32) {
        float z = bl[t];
        for (int d = 0; d < D_; d++) z += pooled[b * D_ + d] * wl[d * 32 + t];
        hb[t] = 0.5f * z * (1.0f + erff(z * 0.70710678118654752f));  // exact gelu
    }
    __syncthreads();
    if (t == 0) {
        float z = bout[0];
        for (int j = 0; j < 32; j++) z += hb[j] * wout[j];
        out[b] = 1.0f / (1.0f + expf(-z));
    }
}

// ---------------------------------------------------------------------------
extern "C" void kernel_launch(void* const* d_in, const int* in_sizes, int n_in,
                              void* d_out, int out_size, void* d_ws, size_t ws_size,
                              hipStream_t stream)
{
    (void)in_sizes; (void)n_in; (void)out_size; (void)ws_size;
    const int*   tokens = (const int*)  d_in[0];
    const float* emb    = (const float*)d_in[1];
    const float* wq     = (const float*)d_in[2];
    const float* bq     = (const float*)d_in[3];
    const float* wk     = (const float*)d_in[4];
    const float* bk     = (const float*)d_in[5];
    const float* wv     = (const float*)d_in[6];
    const float* bv     = (const float*)d_in[7];
    const float* wo     = (const float*)d_in[8];
    const float* bo     = (const float*)d_in[9];
    const float* w1     = (const float*)d_in[10];
    const float* b1     = (const float*)d_in[11];
    const float* w2     = (const float*)d_in[12];
    const float* b2     = (const float*)d_in[13];
    const float* ln1g   = (const float*)d_in[14];
    const float* ln1b   = (const float*)d_in[15];
    const float* ln2g   = (const float*)d_in[16];
    const float* ln2b   = (const float*)d_in[17];
    const float* wl     = (const float*)d_in[18];
    const float* bl     = (const float*)d_in[19];
    const float* wout   = (const float*)d_in[20];
    const float* bout   = (const float*)d_in[21];
    float* out = (float*)d_out;

    char* ws = (char*)d_ws;
    size_t off = 0;
    auto alloc = [&](size_t n) -> float* {
        char* p = ws + off;
        off = (off + n + 255) & ~(size_t)255;
        return (float*)p;
    };
    const size_t XBYTES = (size_t)B_ * S_ * D_ * 4;     // 50.3 MB
    float* pe     = alloc((size_t)S_ * D_ * 4);
    float* x      = alloc(XBYTES);
    float* qb     = alloc(XBYTES);   // also reused as attn_out / ffn_out buffer
    float* kb     = alloc(XBYTES);
    float* vb     = alloc(XBYTES);
    float* avb    = alloc(XBYTES);
    float* hbuf   = alloc((size_t)8192 * FF_ * 4);      // 100.7 MB (FFN chunk)
    float* pooled = alloc((size_t)B_ * D_ * 4);
    // total ~354 MB

    const int M = B_ * S_;                              // 16384
    pe_kernel<<<(S_ * D_ + 255) / 256, 256, 0, stream>>>(pe);
    embed_kernel<<<M, 256, 0, stream>>>(tokens, emb, pe, x);

    for (int l = 0; l < L_; l++) {
        const float* wq_l = wq + (size_t)l * D_ * D_;
        const float* wk_l = wk + (size_t)l * D_ * D_;
        const float* wv_l = wv + (size_t)l * D_ * D_;
        const float* wo_l = wo + (size_t)l * D_ * D_;
        const float* w1_l = w1 + (size_t)l * D_ * FF_;
        const float* w2_l = w2 + (size_t)l * FF_ * D_;
        const float* bq_l = bq + l * D_;
        const float* bk_l = bk + l * D_;
        const float* bv_l = bv + l * D_;
        const float* bo_l = bo + l * D_;
        const float* b1_l = b1 + l * FF_;
        const float* b2_l = b2 + l * D_;

        dim3 gdd(D_ / 128, M / 128);                    // (6,128)
        gemm_bias<<<gdd, 256, 0, stream>>>(x, wq_l, bq_l, qb, M, D_, D_, 0);
        gemm_bias<<<gdd, 256, 0, stream>>>(x, wk_l, bk_l, kb, M, D_, D_, 0);
        gemm_bias<<<gdd, 256, 0, stream>>>(x, wv_l, bv_l, vb, M, D_, D_, 0);

        attn_kernel<<<dim3(S_ / TQ, H_, B_), 256, 0, stream>>>(qb, kb, vb, avb);

        gemm_bias<<<gdd, 256, 0, stream>>>(avb, wo_l, bo_l, qb, M, D_, D_, 0);
        add_ln<<<M, 256, 0, stream>>>(x, qb, ln1g + l * D_, ln1b + l * D_);

        for (int c = 0; c < 2; c++) {                   // FFN in 2 row-chunks
            gemm_bias<<<dim3(FF_ / 128, 8192 / 128), 256, 0, stream>>>(
                x + (size_t)c * 8192 * D_, w1_l, b1_l, hbuf, 8192, FF_, D_, 1);
            gemm_bias<<<dim3(D_ / 128, 8192 / 128), 256, 0, stream>>>(
                hbuf, w2_l, b2_l, qb + (size_t)c * 8192 * D_, 8192, D_, FF_, 0);
        }
        add_ln<<<M, 256, 0, stream>>>(x, qb, ln2g + l * D_, ln2b + l * D_);
    }

    pool_kernel<<<(B_ * D_) / 256, 256, 0, stream>>>(x, pooled);
    head_kernel<<<B_, 64, 0, stream>>>(pooled, wl, bl, wout, bout, out);
}

// Round 2
// 7991.811 us; speedup vs baseline: 2.1977x; 2.1977x over previous
//
#include <hip/hip_runtime.h>
#include <hip/hip_bf16.h>
#include <math.h>

// ---------------------------------------------------------------------------
// TextTransformer forward on MI355X — Round 2: bf16 MFMA GEMMs (m97 pattern).
// B=32 S=512 D=768 H=12 DH=64 FF=3072 L=4.
// GEMMs: 128x128 tile, mfma_f32_16x16x32_bf16, BK=32, global_load_lds w=16,
//        B^T (pre-transposed bf16 weights) so A and B frags are ds_read_b128.
// Attention: unchanged fp32 kernel (next round's target); writes bf16 av.
// Residual/LN path stays fp32; producers write bf16 mirrors for GEMM inputs.
// ---------------------------------------------------------------------------

#define B_  32
#define S_  512
#define D_  768
#define H_  12
#define DH_ 64
#define FF_ 3072
#define L_  4

typedef __attribute__((ext_vector_type(8))) short short8;   // 8 x bf16
typedef __attribute__((ext_vector_type(4))) float f32x4;

__device__ __forceinline__ void async16(const void* g, void* l) {
    __builtin_amdgcn_global_load_lds(
        (const __attribute__((address_space(1))) void*)g,
        (__attribute__((address_space(3))) void*)l, 16, 0, 0);
}

// ----------------------------- positional encoding -------------------------
__global__ void pe_kernel(float* __restrict__ pe) {
    int idx = blockIdx.x * 256 + threadIdx.x;
    if (idx >= S_ * D_) return;
    int s = idx / D_, j = idx % D_;
    double e = (2.0 * (double)(j >> 1)) / (double)D_;
    double denom = pow(10000.0, e);
    double ang = (double)s / denom;
    pe[idx] = (j & 1) ? (float)cos(ang) : (float)sin(ang);
}

// ----------------------------- embedding + PE ------------------------------
__global__ void embed_kernel(const int* __restrict__ tokens,
                             const float* __restrict__ emb,
                             const float* __restrict__ pe,
                             float* __restrict__ x,
                             __hip_bfloat16* __restrict__ xb) {
    int row = blockIdx.x;              // b*S + s
    int s = row & (S_ - 1);
    int tok = tokens[row];
    float scale = sqrtf((float)D_);
    for (int i = threadIdx.x; i < D_; i += 256) {
        float v = emb[(size_t)tok * D_ + i] * scale + pe[s * D_ + i];
        x[(size_t)row * D_ + i] = v;
        xb[(size_t)row * D_ + i] = __float2bfloat16(v);
    }
}

// ----------------------------- weight transpose fp32->bf16 -----------------
// out[c][r] = (bf16) in[r][c].  R, C multiples of 32. Grid (C/32, R/32).
__global__ __launch_bounds__(256) void transpose_bf16(
    const float* __restrict__ in, __hip_bfloat16* __restrict__ out, int R, int C)
{
    __shared__ float tile[32][33];
    int tx = threadIdx.x & 31, ty = threadIdx.x >> 5;   // 32 x 8
    int c0 = blockIdx.x * 32, r0 = blockIdx.y * 32;
#pragma unroll
    for (int d = 0; d < 32; d += 8)
        tile[ty + d][tx] = in[(size_t)(r0 + ty + d) * C + c0 + tx];
    __syncthreads();
#pragma unroll
    for (int d = 0; d < 32; d += 8)
        out[(size_t)(c0 + ty + d) * R + r0 + tx] = __float2bfloat16(tile[tx][ty + d]);
}

// ----------------------------- bf16 MFMA GEMM ------------------------------
// C[M,N] = A[M,K] @ Bt[N,K]^T + bias[N].  M%128==0, N%128==0, K%32==0.
// 256 thr = 4 waves in 2x2; each wave 64x64 = 4x4 tiles of 16x16x32 MFMA.
template<int OUT_BF16, int RELU>
__global__ __launch_bounds__(256) void gemm_mfma(
    const ushort* __restrict__ A,   // bf16 [M][K]
    const ushort* __restrict__ Bt,  // bf16 [N][K]
    const float* __restrict__ bias, // fp32 [N]
    void* __restrict__ Cout,        // fp32 or bf16 [M][N]
    int M, int N, int K)
{
    __shared__ alignas(16) ushort sA[128 * 32];
    __shared__ alignas(16) ushort sB[128 * 32];
    int t = threadIdx.x;
    int n0 = blockIdx.x * 128, m0 = blockIdx.y * 128;
    int l = t & 63, w = t >> 6;
    int wm = (w >> 1) * 64, wn = (w & 1) * 64;

    // staging: thread t, issue i -> 8 consecutive bf16 (16 B)
    int idx0 = t * 8;
    int row0 = idx0 >> 5, col0 = idx0 & 31;
    int idx1 = idx0 + 2048;
    int row1 = idx1 >> 5, col1 = idx1 & 31;
    const ushort* Ab = A + (size_t)m0 * K;
    const ushort* Bb = Bt + (size_t)n0 * K;

    int lm = l & 15, lq = l >> 4;
    int aoff = (wm + lm) * 32 + lq * 8;   // element offset; +i*512 per tile row
    int boff = (wn + lm) * 32 + lq * 8;

    f32x4 acc[4][4];
#pragma unroll
    for (int i = 0; i < 4; i++)
#pragma unroll
        for (int j = 0; j < 4; j++) acc[i][j] = (f32x4){0.f, 0.f, 0.f, 0.f};

    for (int k0 = 0; k0 < K; k0 += 32) {
        __syncthreads();   // prev-iter LDS reads complete before overwrite
        async16(Ab + (size_t)row0 * K + k0 + col0, &sA[idx0]);
        async16(Ab + (size_t)row1 * K + k0 + col1, &sA[idx1]);
        async16(Bb + (size_t)row0 * K + k0 + col0, &sB[idx0]);
        async16(Bb + (size_t)row1 * K + k0 + col1, &sB[idx1]);
        __syncthreads();   // drains vmcnt + barrier
        short8 a[4], b[4];
#pragma unroll
        for (int i = 0; i < 4; i++) a[i] = *(const short8*)&sA[aoff + i * 512];
#pragma unroll
        for (int j = 0; j < 4; j++) b[j] = *(const short8*)&sB[boff + j * 512];
#pragma unroll
        for (int i = 0; i < 4; i++)
#pragma unroll
            for (int j = 0; j < 4; j++)
                acc[i][j] = __builtin_amdgcn_mfma_f32_16x16x32_bf16(
                    a[i], b[j], acc[i][j], 0, 0, 0);
    }

    // epilogue: C/D layout col=lane&15, row=(lane>>4)*4+reg
    int rb = m0 + wm + lq * 4;
    int cb = n0 + wn + lm;
#pragma unroll
    for (int j = 0; j < 4; j++) {
        int c = cb + j * 16;
        float bs = bias[c];
#pragma unroll
        for (int i = 0; i < 4; i++) {
#pragma unroll
            for (int r = 0; r < 4; r++) {
                float v = acc[i][j][r] + bs;
                if (RELU) v = fmaxf(v, 0.f);
                size_t o = (size_t)(rb + i * 16 + r) * N + c;
                if (OUT_BF16) ((__hip_bfloat16*)Cout)[o] = __float2bfloat16(v);
                else          ((float*)Cout)[o] = v;
            }
        }
    }
}

// ----------------------------- fused attention (fp32, unchanged) -----------
#define TQ 16
__global__ __launch_bounds__(256) void attn_kernel(
    const float* __restrict__ q, const float* __restrict__ k,
    const float* __restrict__ v, __hip_bfloat16* __restrict__ av)
{
    __shared__ alignas(16) float sQ[TQ][68];
    __shared__ alignas(16) float sKV[64][68];
    __shared__ float sS[TQ][513];
    __shared__ float red[TQ][16];
    __shared__ float rowstat[TQ];
    int t = threadIdx.x;
    int qt = blockIdx.x, h = blockIdx.y, b = blockIdx.z;
    int tx = t & 15, ty = t >> 4;

    for (int i = t; i < TQ * DH_; i += 256) {
        int rr = i >> 6, d = i & 63;
        sQ[rr][d] = q[(size_t)(b * S_ + qt * TQ + rr) * D_ + h * DH_ + d];
    }
    int c = tx * 4;
    for (int kt = 0; kt < S_ / 64; kt++) {
        __syncthreads();
        for (int i = t; i < 64 * DH_; i += 256) {
            int rr = i >> 6, d = i & 63;
            sKV[rr][d] = k[(size_t)(b * S_ + kt * 64 + rr) * D_ + h * DH_ + d];
        }
        __syncthreads();
        float a0 = 0, a1 = 0, a2 = 0, a3 = 0;
#pragma unroll
        for (int d4 = 0; d4 < 16; d4++) {
            float4 q4 = *(float4*)&sQ[ty][d4 * 4];
            float4 k0 = *(float4*)&sKV[c + 0][d4 * 4];
            float4 k1 = *(float4*)&sKV[c + 1][d4 * 4];
            float4 k2 = *(float4*)&sKV[c + 2][d4 * 4];
            float4 k3 = *(float4*)&sKV[c + 3][d4 * 4];
            a0 += q4.x * k0.x + q4.y * k0.y + q4.z * k0.z + q4.w * k0.w;
            a1 += q4.x * k1.x + q4.y * k1.y + q4.z * k1.z + q4.w * k1.w;
            a2 += q4.x * k2.x + q4.y * k2.y + q4.z * k2.z + q4.w * k2.w;
            a3 += q4.x * k3.x + q4.y * k3.y + q4.z * k3.z + q4.w * k3.w;
        }
        sS[ty][kt * 64 + c + 0] = a0 * 0.125f;
        sS[ty][kt * 64 + c + 1] = a1 * 0.125f;
        sS[ty][kt * 64 + c + 2] = a2 * 0.125f;
        sS[ty][kt * 64 + c + 3] = a3 * 0.125f;
    }
    __syncthreads();
    float mx = -1e30f;
    for (int m2 = 0; m2 < 32; m2++) mx = fmaxf(mx, sS[ty][tx + m2 * 16]);
    red[ty][tx] = mx;
    __syncthreads();
    if (tx == 0) {
        float mm = red[ty][0];
        for (int j2 = 1; j2 < 16; j2++) mm = fmaxf(mm, red[ty][j2]);
        rowstat[ty] = mm;
    }
    __syncthreads();
    float rm = rowstat[ty];
    float sum = 0.f;
    for (int m2 = 0; m2 < 32; m2++) {
        float e = __expf(sS[ty][tx + m2 * 16] - rm);
        sS[ty][tx + m2 * 16] = e;
        sum += e;
    }
    red[ty][tx] = sum;
    __syncthreads();
    if (tx == 0) {
        float ss = 0.f;
        for (int j2 = 0; j2 < 16; j2++) ss += red[ty][j2];
        rowstat[ty] = ss;
    }
    __syncthreads();
    float inv = 1.0f / rowstat[ty];
    for (int m2 = 0; m2 < 32; m2++) sS[ty][tx + m2 * 16] *= inv;
    float o0 = 0, o1 = 0, o2 = 0, o3 = 0;
    for (int kt = 0; kt < S_ / 64; kt++) {
        __syncthreads();
        for (int i = t; i < 64 * DH_; i += 256) {
            int rr = i >> 6, d = i & 63;
            sKV[rr][d] = v[(size_t)(b * S_ + kt * 64 + rr) * D_ + h * DH_ + d];
        }
        __syncthreads();
#pragma unroll 8
        for (int kk = 0; kk < 64; kk++) {
            float p = sS[ty][kt * 64 + kk];
            float4 v4 = *(float4*)&sKV[kk][tx * 4];
            o0 += p * v4.x; o1 += p * v4.y; o2 += p * v4.z; o3 += p * v4.w;
        }
    }
    size_t ob = (size_t)(b * S_ + qt * TQ + ty) * D_ + h * DH_ + tx * 4;
    av[ob + 0] = __float2bfloat16(o0);
    av[ob + 1] = __float2bfloat16(o1);
    av[ob + 2] = __float2bfloat16(o2);
    av[ob + 3] = __float2bfloat16(o3);
}

// ----------------------------- residual + layernorm ------------------------
__global__ __launch_bounds__(256) void add_ln(float* __restrict__ x,
    __hip_bfloat16* __restrict__ xb,
    const float* __restrict__ r, const float* __restrict__ g,
    const float* __restrict__ bta)
{
    __shared__ float sred[256];
    int row = blockIdx.x, t = threadIdx.x;
    size_t base = (size_t)row * D_;
    float v0 = x[base + t]       + r[base + t];
    float v1 = x[base + t + 256] + r[base + t + 256];
    float v2 = x[base + t + 512] + r[base + t + 512];
    sred[t] = v0 + v1 + v2;
    __syncthreads();
    for (int o = 128; o > 0; o >>= 1) { if (t < o) sred[t] += sred[t + o]; __syncthreads(); }
    float mean = sred[0] * (1.0f / D_);
    __syncthreads();
    float d0 = v0 - mean, d1 = v1 - mean, d2 = v2 - mean;
    sred[t] = d0 * d0 + d1 * d1 + d2 * d2;
    __syncthreads();
    for (int o = 128; o > 0; o >>= 1) { if (t < o) sred[t] += sred[t + o]; __syncthreads(); }
    float rstd = rsqrtf(sred[0] * (1.0f / D_) + 1e-6f);
    float o0 = g[t]       * d0 * rstd + bta[t];
    float o1 = g[t + 256] * d1 * rstd + bta[t + 256];
    float o2 = g[t + 512] * d2 * rstd + bta[t + 512];
    x[base + t]       = o0;
    x[base + t + 256] = o1;
    x[base + t + 512] = o2;
    xb[base + t]       = __float2bfloat16(o0);
    xb[base + t + 256] = __float2bfloat16(o1);
    xb[base + t + 512] = __float2bfloat16(o2);
}

// ----------------------------- mean pool over S ----------------------------
__global__ void pool_kernel(const float* __restrict__ x, float* __restrict__ pooled) {
    int idx = blockIdx.x * 256 + threadIdx.x;   // b*768 + d
    int b = idx / D_, d = idx % D_;
    float acc = 0.f;
    const float* p = x + (size_t)b * S_ * D_ + d;
    for (int s = 0; s < S_; s++) acc += p[(size_t)s * D_];
    pooled[idx] = acc * (1.0f / S_);
}

// ----------------------------- classifier head -----------------------------
__global__ void head_kernel(const float* __restrict__ pooled,
                            const float* __restrict__ wl,
                            const float* __restrict__ bl,
                            const float* __restrict__ wout,
                            const float* __restrict__ bout,
                            float* __restrict__ out)
{
    __shared__ float hb[32];
    int b = blockIdx.x, t = threadIdx.x;
    if (t < 32) {
        float z = bl[t];
        for (int d = 0; d < D_; d++) z += pooled[b * D_ + d] * wl[d * 32 + t];
        hb[t] = 0.5f * z * (1.0f + erff(z * 0.70710678118654752f));  // exact gelu
    }
    __syncthreads();
    if (t == 0) {
        float z = bout[0];
        for (int j = 0; j < 32; j++) z += hb[j] * wout[j];
        out[b] = 1.0f / (1.0f + expf(-z));
    }
}

// ---------------------------------------------------------------------------
extern "C" void kernel_launch(void* const* d_in, const int* in_sizes, int n_in,
                              void* d_out, int out_size, void* d_ws, size_t ws_size,
                              hipStream_t stream)
{
    (void)in_sizes; (void)n_in; (void)out_size; (void)ws_size;
    const int*   tokens = (const int*)  d_in[0];
    const float* emb    = (const float*)d_in[1];
    const float* wq     = (const float*)d_in[2];
    const float* bq     = (const float*)d_in[3];
    const float* wk     = (const float*)d_in[4];
    const float* bk     = (const float*)d_in[5];
    const float* wv     = (const float*)d_in[6];
    const float* bv     = (const float*)d_in[7];
    const float* wo     = (const float*)d_in[8];
    const float* bo     = (const float*)d_in[9];
    const float* w1     = (const float*)d_in[10];
    const float* b1     = (const float*)d_in[11];
    const float* w2     = (const float*)d_in[12];
    const float* b2     = (const float*)d_in[13];
    const float* ln1g   = (const float*)d_in[14];
    const float* ln1b   = (const float*)d_in[15];
    const float* ln2g   = (const float*)d_in[16];
    const float* ln2b   = (const float*)d_in[17];
    const float* wl     = (const float*)d_in[18];
    const float* bl     = (const float*)d_in[19];
    const float* wout   = (const float*)d_in[20];
    const float* bout   = (const float*)d_in[21];
    float* out = (float*)d_out;

    char* ws = (char*)d_ws;
    size_t off = 0;
    auto alloc = [&](size_t n) -> void* {
        char* p = ws + off;
        off = (off + n + 255) & ~(size_t)255;
        return (void*)p;
    };
    const size_t XBYTES = (size_t)B_ * S_ * D_ * 4;        // 50.33 MB
    float*          pe     = (float*)alloc((size_t)S_ * D_ * 4);
    float*          x      = (float*)alloc(XBYTES);
    __hip_bfloat16* xb     = (__hip_bfloat16*)alloc(XBYTES / 2);
    float*          qb     = (float*)alloc(XBYTES);        // q / attn_out / ffn_out
    float*          kb     = (float*)alloc(XBYTES);        // k; aliased by h_bf
    float*          vb     = (float*)alloc(XBYTES);        // v; aliased by h_bf
    __hip_bfloat16* h_bf   = (__hip_bfloat16*)kb;          // 16384*3072 bf16 == kb+vb
    __hip_bfloat16* av_bf  = (__hip_bfloat16*)alloc(XBYTES / 2);
    __hip_bfloat16* wT     = (__hip_bfloat16*)alloc((size_t)L_ * 7077888 * 2); // 56.6 MB
    float*          pooled = (float*)alloc((size_t)B_ * D_ * 4);
    // total ~310 MB

    const int M = B_ * S_;                                 // 16384
    const size_t DD = (size_t)D_ * D_;                     // 589824
    const size_t DF = (size_t)D_ * FF_;                    // 2359296
    const size_t LSTRIDE = 4 * DD + 2 * DF;                // 7077888

    // ---- one-time weight transpose+convert (per launch; weights are inputs)
    for (int l = 0; l < L_; l++) {
        __hip_bfloat16* wl_base = wT + (size_t)l * LSTRIDE;
        transpose_bf16<<<dim3(D_ / 32, D_ / 32), 256, 0, stream>>>(
            wq + l * DD, wl_base + 0 * DD, D_, D_);
        transpose_bf16<<<dim3(D_ / 32, D_ / 32), 256, 0, stream>>>(
            wk + l * DD, wl_base + 1 * DD, D_, D_);
        transpose_bf16<<<dim3(D_ / 32, D_ / 32), 256, 0, stream>>>(
            wv + l * DD, wl_base + 2 * DD, D_, D_);
        transpose_bf16<<<dim3(D_ / 32, D_ / 32), 256, 0, stream>>>(
            wo + l * DD, wl_base + 3 * DD, D_, D_);
        transpose_bf16<<<dim3(FF_ / 32, D_ / 32), 256, 0, stream>>>(
            w1 + l * DF, wl_base + 4 * DD, D_, FF_);            // -> [3072][768]
        transpose_bf16<<<dim3(D_ / 32, FF_ / 32), 256, 0, stream>>>(
            w2 + l * DF, wl_base + 4 * DD + DF, FF_, D_);       // -> [768][3072]
    }

    pe_kernel<<<(S_ * D_ + 255) / 256, 256, 0, stream>>>(pe);
    embed_kernel<<<M, 256, 0, stream>>>(tokens, emb, pe, x, xb);

    for (int l = 0; l < L_; l++) {
        __hip_bfloat16* wl_base = wT + (size_t)l * LSTRIDE;
        const ushort* wqT = (const ushort*)(wl_base + 0 * DD);
        const ushort* wkT = (const ushort*)(wl_base + 1 * DD);
        const ushort* wvT = (const ushort*)(wl_base + 2 * DD);
        const ushort* woT = (const ushort*)(wl_base + 3 * DD);
        const ushort* w1T = (const ushort*)(wl_base + 4 * DD);
        const ushort* w2T = (const ushort*)(wl_base + 4 * DD + DF);

        dim3 gdd(D_ / 128, M / 128);                       // (6,128)
        gemm_mfma<0,0><<<gdd, 256, 0, stream>>>(
            (const ushort*)xb, wqT, bq + l * D_, qb, M, D_, D_);
        gemm_mfma<0,0><<<gdd, 256, 0, stream>>>(
            (const ushort*)xb, wkT, bk + l * D_, kb, M, D_, D_);
        gemm_mfma<0,0><<<gdd, 256, 0, stream>>>(
            (const ushort*)xb, wvT, bv + l * D_, vb, M, D_, D_);

        attn_kernel<<<dim3(S_ / TQ, H_, B_), 256, 0, stream>>>(qb, kb, vb, av_bf);

        gemm_mfma<0,0><<<gdd, 256, 0, stream>>>(
            (const ushort*)av_bf, woT, bo + l * D_, qb, M, D_, D_);
        add_ln<<<M, 256, 0, stream>>>(x, xb, qb, ln1g + l * D_, ln1b + l * D_);

        gemm_mfma<1,1><<<dim3(FF_ / 128, M / 128), 256, 0, stream>>>(
            (const ushort*)xb, w1T, b1 + l * FF_, h_bf, M, FF_, D_);
        gemm_mfma<0,0><<<dim3(D_ / 128, M / 128), 256, 0, stream>>>(
            (const ushort*)h_bf, w2T, b2 + l * D_, qb, M, D_, FF_);
        add_ln<<<M, 256, 0, stream>>>(x, xb, qb, ln2g + l * D_, ln2b + l * D_);
    }

    pool_kernel<<<(B_ * D_) / 256, 256, 0, stream>>>(x, pooled);
    head_kernel<<<B_, 64, 0, stream>>>(pooled, wl, bl, wout, bout, out);
}

// Round 3
// 2512.163 us; speedup vs baseline: 6.9913x; 3.1812x over previous
//
#include <hip/hip_runtime.h>
#include <hip/hip_bf16.h>
#include <math.h>

// ---------------------------------------------------------------------------
// TextTransformer forward on MI355X — Round 3: MFMA flash attention.
// B=32 S=512 D=768 H=12 DH=64 FF=3072 L=4.
// GEMMs: m97 pattern (128x128, mfma 16x16x32_bf16, BK=32, global_load_lds 16).
// Attention: bf16 MFMA flash: per (128q, h, b) block; K-tile=64; online
//   softmax with shfl butterflies; P via wave-local LDS; V transposed at stage.
// ---------------------------------------------------------------------------

#define B_  32
#define S_  512
#define D_  768
#define H_  12
#define DH_ 64
#define FF_ 3072
#define L_  4

typedef __attribute__((ext_vector_type(8))) short short8;   // 8 x bf16
typedef __attribute__((ext_vector_type(4))) float f32x4;

__device__ __forceinline__ void async16(const void* g, void* l) {
    __builtin_amdgcn_global_load_lds(
        (const __attribute__((address_space(1))) void*)g,
        (__attribute__((address_space(3))) void*)l, 16, 0, 0);
}

__device__ __forceinline__ ushort f2bf(float f) {
    __hip_bfloat16 h = __float2bfloat16(f);
    return __builtin_bit_cast(ushort, h);
}

// ----------------------------- positional encoding -------------------------
__global__ void pe_kernel(float* __restrict__ pe) {
    int idx = blockIdx.x * 256 + threadIdx.x;
    if (idx >= S_ * D_) return;
    int s = idx / D_, j = idx % D_;
    double e = (2.0 * (double)(j >> 1)) / (double)D_;
    double denom = pow(10000.0, e);
    double ang = (double)s / denom;
    pe[idx] = (j & 1) ? (float)cos(ang) : (float)sin(ang);
}

// ----------------------------- embedding + PE ------------------------------
__global__ void embed_kernel(const int* __restrict__ tokens,
                             const float* __restrict__ emb,
                             const float* __restrict__ pe,
                             float* __restrict__ x,
                             __hip_bfloat16* __restrict__ xb) {
    int row = blockIdx.x;              // b*S + s
    int s = row & (S_ - 1);
    int tok = tokens[row];
    float scale = sqrtf((float)D_);
    for (int i = threadIdx.x; i < D_; i += 256) {
        float v = emb[(size_t)tok * D_ + i] * scale + pe[s * D_ + i];
        x[(size_t)row * D_ + i] = v;
        xb[(size_t)row * D_ + i] = __float2bfloat16(v);
    }
}

// ----------------------------- weight transpose fp32->bf16 -----------------
__global__ __launch_bounds__(256) void transpose_bf16(
    const float* __restrict__ in, __hip_bfloat16* __restrict__ out, int R, int C)
{
    __shared__ float tile[32][33];
    int tx = threadIdx.x & 31, ty = threadIdx.x >> 5;   // 32 x 8
    int c0 = blockIdx.x * 32, r0 = blockIdx.y * 32;
#pragma unroll
    for (int d = 0; d < 32; d += 8)
        tile[ty + d][tx] = in[(size_t)(r0 + ty + d) * C + c0 + tx];
    __syncthreads();
#pragma unroll
    for (int d = 0; d < 32; d += 8)
        out[(size_t)(c0 + ty + d) * R + r0 + tx] = __float2bfloat16(tile[tx][ty + d]);
}

// ----------------------------- bf16 MFMA GEMM ------------------------------
// C[M,N] = A[M,K] @ Bt[N,K]^T + bias[N].  M%128==0, N%128==0, K%32==0.
template<int OUT_BF16, int RELU>
__global__ __launch_bounds__(256) void gemm_mfma(
    const ushort* __restrict__ A,   // bf16 [M][K]
    const ushort* __restrict__ Bt,  // bf16 [N][K]
    const float* __restrict__ bias, // fp32 [N]
    void* __restrict__ Cout,        // fp32 or bf16 [M][N]
    int M, int N, int K)
{
    __shared__ alignas(16) ushort sA[128 * 32];
    __shared__ alignas(16) ushort sB[128 * 32];
    int t = threadIdx.x;
    int n0 = blockIdx.x * 128, m0 = blockIdx.y * 128;
    int l = t & 63, w = t >> 6;
    int wm = (w >> 1) * 64, wn = (w & 1) * 64;

    int idx0 = t * 8;
    int row0 = idx0 >> 5, col0 = idx0 & 31;
    int idx1 = idx0 + 2048;
    int row1 = idx1 >> 5, col1 = idx1 & 31;
    const ushort* Ab = A + (size_t)m0 * K;
    const ushort* Bb = Bt + (size_t)n0 * K;

    int lm = l & 15, lq = l >> 4;
    int aoff = (wm + lm) * 32 + lq * 8;
    int boff = (wn + lm) * 32 + lq * 8;

    f32x4 acc[4][4];
#pragma unroll
    for (int i = 0; i < 4; i++)
#pragma unroll
        for (int j = 0; j < 4; j++) acc[i][j] = (f32x4){0.f, 0.f, 0.f, 0.f};

    for (int k0 = 0; k0 < K; k0 += 32) {
        __syncthreads();
        async16(Ab + (size_t)row0 * K + k0 + col0, &sA[idx0]);
        async16(Ab + (size_t)row1 * K + k0 + col1, &sA[idx1]);
        async16(Bb + (size_t)row0 * K + k0 + col0, &sB[idx0]);
        async16(Bb + (size_t)row1 * K + k0 + col1, &sB[idx1]);
        __syncthreads();
        short8 a[4], b[4];
#pragma unroll
        for (int i = 0; i < 4; i++) a[i] = *(const short8*)&sA[aoff + i * 512];
#pragma unroll
        for (int j = 0; j < 4; j++) b[j] = *(const short8*)&sB[boff + j * 512];
#pragma unroll
        for (int i = 0; i < 4; i++)
#pragma unroll
            for (int j = 0; j < 4; j++)
                acc[i][j] = __builtin_amdgcn_mfma_f32_16x16x32_bf16(
                    a[i], b[j], acc[i][j], 0, 0, 0);
    }

    int rb = m0 + wm + lq * 4;
    int cb = n0 + wn + lm;
#pragma unroll
    for (int j = 0; j < 4; j++) {
        int c = cb + j * 16;
        float bs = bias[c];
#pragma unroll
        for (int i = 0; i < 4; i++) {
#pragma unroll
            for (int r = 0; r < 4; r++) {
                float v = acc[i][j][r] + bs;
                if (RELU) v = fmaxf(v, 0.f);
                size_t o = (size_t)(rb + i * 16 + r) * N + c;
                if (OUT_BF16) ((__hip_bfloat16*)Cout)[o] = __float2bfloat16(v);
                else          ((float*)Cout)[o] = v;
            }
        }
    }
}

// ----------------------------- MFMA flash attention ------------------------
// Block: (qt of 128 rows, h, b); 4 waves; wave w owns q-rows wm=w*32..+32.
// Loop 8 K-tiles of 64. All LDS rows stride 72 bf16 (144 B, 16B-aligned).
#define PSTR 72
__global__ __launch_bounds__(256) void attn_mfma(
    const ushort* __restrict__ q,   // bf16 [B*S][D]
    const ushort* __restrict__ k,
    const ushort* __restrict__ v,
    __hip_bfloat16* __restrict__ av)
{
    __shared__ alignas(16) ushort sQ[128 * PSTR];
    __shared__ alignas(16) ushort sK[64 * PSTR];
    __shared__ alignas(16) ushort sVt[64 * PSTR];   // Vt[d][s]
    __shared__ alignas(16) ushort sP[4][32 * PSTR];

    int t = threadIdx.x;
    int qt = blockIdx.x, h = blockIdx.y, b = blockIdx.z;
    int w = t >> 6, l = t & 63;
    int lm = l & 15, lq = l >> 4;
    int wm = w * 32;

    const ushort* qbase = q + (size_t)(b * S_ + qt * 128) * D_ + h * DH_;
    const ushort* kbase = k + (size_t)b * S_ * D_ + h * DH_;
    const ushort* vbase = v + (size_t)b * S_ * D_ + h * DH_;

    // stage Q tile [128][64]
    {
        int r = t >> 1, c0 = (t & 1) * 32;
        const ushort* src = qbase + (size_t)r * D_ + c0;
        ushort* dst = &sQ[r * PSTR + c0];
        *(uint4*)(dst + 0)  = *(const uint4*)(src + 0);
        *(uint4*)(dst + 8)  = *(const uint4*)(src + 8);
        *(uint4*)(dst + 16) = *(const uint4*)(src + 16);
        *(uint4*)(dst + 24) = *(const uint4*)(src + 24);
    }
    __syncthreads();
    short8 qf[2][2];
#pragma unroll
    for (int i = 0; i < 2; i++)
#pragma unroll
        for (int ks = 0; ks < 2; ks++)
            qf[i][ks] = *(const short8*)&sQ[(wm + i * 16 + lm) * PSTR + ks * 32 + lq * 8];

    f32x4 accO[2][4];
    float mrun[2][4], lrun[2][4];
#pragma unroll
    for (int i = 0; i < 2; i++)
#pragma unroll
        for (int j = 0; j < 4; j++) accO[i][j] = (f32x4){0.f, 0.f, 0.f, 0.f};
#pragma unroll
    for (int i = 0; i < 2; i++)
#pragma unroll
        for (int r = 0; r < 4; r++) { mrun[i][r] = -1e30f; lrun[i][r] = 0.f; }

    for (int kt = 0; kt < S_ / 64; kt++) {
        __syncthreads();   // prior reads of sK/sVt done
        {
            int r = t >> 2, c0 = (t & 3) * 16;
            const ushort* ksrc = kbase + (size_t)(kt * 64 + r) * D_ + c0;
            ushort* kdst = &sK[r * PSTR + c0];
            *(uint4*)(kdst + 0) = *(const uint4*)(ksrc + 0);
            *(uint4*)(kdst + 8) = *(const uint4*)(ksrc + 8);
            const ushort* vsrc = vbase + (size_t)(kt * 64 + r) * D_ + c0;
            ushort vv[16];
            *(uint4*)&vv[0] = *(const uint4*)(vsrc + 0);
            *(uint4*)&vv[8] = *(const uint4*)(vsrc + 8);
#pragma unroll
            for (int j = 0; j < 16; j++) sVt[(c0 + j) * PSTR + r] = vv[j];
        }
        __syncthreads();

        // S = Q K^T (scaled)
        f32x4 accS[2][4];
#pragma unroll
        for (int i = 0; i < 2; i++)
#pragma unroll
            for (int j = 0; j < 4; j++) accS[i][j] = (f32x4){0.f, 0.f, 0.f, 0.f};
#pragma unroll
        for (int ks = 0; ks < 2; ks++) {
#pragma unroll
            for (int j = 0; j < 4; j++) {
                short8 kf = *(const short8*)&sK[(j * 16 + lm) * PSTR + ks * 32 + lq * 8];
#pragma unroll
                for (int i = 0; i < 2; i++)
                    accS[i][j] = __builtin_amdgcn_mfma_f32_16x16x32_bf16(
                        qf[i][ks], kf, accS[i][j], 0, 0, 0);
            }
        }
#pragma unroll
        for (int i = 0; i < 2; i++)
#pragma unroll
            for (int j = 0; j < 4; j++)
#pragma unroll
                for (int r = 0; r < 4; r++) accS[i][j][r] *= 0.125f;

        // online softmax
        float rmax[2][4];
#pragma unroll
        for (int i = 0; i < 2; i++)
#pragma unroll
            for (int r = 0; r < 4; r++) {
                float m0 = fmaxf(fmaxf(accS[i][0][r], accS[i][1][r]),
                                 fmaxf(accS[i][2][r], accS[i][3][r]));
                rmax[i][r] = m0;
            }
#pragma unroll
        for (int d = 1; d < 16; d <<= 1)
#pragma unroll
            for (int i = 0; i < 2; i++)
#pragma unroll
                for (int r = 0; r < 4; r++)
                    rmax[i][r] = fmaxf(rmax[i][r], __shfl_xor(rmax[i][r], d));

        float alpha[2][4];
#pragma unroll
        for (int i = 0; i < 2; i++)
#pragma unroll
            for (int r = 0; r < 4; r++) {
                float mn = fmaxf(mrun[i][r], rmax[i][r]);
                alpha[i][r] = __expf(mrun[i][r] - mn);
                mrun[i][r] = mn;
            }
        float rsum[2][4];
#pragma unroll
        for (int i = 0; i < 2; i++)
#pragma unroll
            for (int r = 0; r < 4; r++) rsum[i][r] = 0.f;
#pragma unroll
        for (int i = 0; i < 2; i++)
#pragma unroll
            for (int j = 0; j < 4; j++)
#pragma unroll
                for (int r = 0; r < 4; r++) {
                    float p = __expf(accS[i][j][r] - mrun[i][r]);
                    accS[i][j][r] = p;
                    rsum[i][r] += p;
                }
#pragma unroll
        for (int d = 1; d < 16; d <<= 1)
#pragma unroll
            for (int i = 0; i < 2; i++)
#pragma unroll
                for (int r = 0; r < 4; r++)
                    rsum[i][r] += __shfl_xor(rsum[i][r], d);
#pragma unroll
        for (int i = 0; i < 2; i++)
#pragma unroll
            for (int r = 0; r < 4; r++)
                lrun[i][r] = lrun[i][r] * alpha[i][r] + rsum[i][r];

        // rescale O
#pragma unroll
        for (int i = 0; i < 2; i++)
#pragma unroll
            for (int j = 0; j < 4; j++)
#pragma unroll
                for (int r = 0; r < 4; r++) accO[i][j][r] *= alpha[i][r];

        // P -> wave-local LDS (C-layout -> A-layout round trip; no barrier)
#pragma unroll
        for (int i = 0; i < 2; i++)
#pragma unroll
            for (int j = 0; j < 4; j++)
#pragma unroll
                for (int r = 0; r < 4; r++)
                    sP[w][(i * 16 + lq * 4 + r) * PSTR + j * 16 + lm] =
                        f2bf(accS[i][j][r]);

        // O += P V   (B-frags from Vt[d][s])
#pragma unroll
        for (int ks = 0; ks < 2; ks++) {
            short8 pf[2];
#pragma unroll
            for (int i = 0; i < 2; i++)
                pf[i] = *(const short8*)&sP[w][(i * 16 + lm) * PSTR + ks * 32 + lq * 8];
#pragma unroll
            for (int j = 0; j < 4; j++) {
                short8 vf = *(const short8*)&sVt[(j * 16 + lm) * PSTR + ks * 32 + lq * 8];
#pragma unroll
                for (int i = 0; i < 2; i++)
                    accO[i][j] = __builtin_amdgcn_mfma_f32_16x16x32_bf16(
                        pf[i], vf, accO[i][j], 0, 0, 0);
            }
        }
    }

    // epilogue
    float invl[2][4];
#pragma unroll
    for (int i = 0; i < 2; i++)
#pragma unroll
        for (int r = 0; r < 4; r++) invl[i][r] = 1.0f / lrun[i][r];
#pragma unroll
    for (int i = 0; i < 2; i++)
#pragma unroll
        for (int j = 0; j < 4; j++)
#pragma unroll
            for (int r = 0; r < 4; r++) {
                int row = qt * 128 + wm + i * 16 + lq * 4 + r;
                int col = h * DH_ + j * 16 + lm;
                av[(size_t)(b * S_ + row) * D_ + col] =
                    __float2bfloat16(accO[i][j][r] * invl[i][r]);
            }
}

// ----------------------------- residual + layernorm ------------------------
__global__ __launch_bounds__(256) void add_ln(float* __restrict__ x,
    __hip_bfloat16* __restrict__ xb,
    const float* __restrict__ r, const float* __restrict__ g,
    const float* __restrict__ bta)
{
    __shared__ float sred[256];
    int row = blockIdx.x, t = threadIdx.x;
    size_t base = (size_t)row * D_;
    float v0 = x[base + t]       + r[base + t];
    float v1 = x[base + t + 256] + r[base + t + 256];
    float v2 = x[base + t + 512] + r[base + t + 512];
    sred[t] = v0 + v1 + v2;
    __syncthreads();
    for (int o = 128; o > 0; o >>= 1) { if (t < o) sred[t] += sred[t + o]; __syncthreads(); }
    float mean = sred[0] * (1.0f / D_);
    __syncthreads();
    float d0 = v0 - mean, d1 = v1 - mean, d2 = v2 - mean;
    sred[t] = d0 * d0 + d1 * d1 + d2 * d2;
    __syncthreads();
    for (int o = 128; o > 0; o >>= 1) { if (t < o) sred[t] += sred[t + o]; __syncthreads(); }
    float rstd = rsqrtf(sred[0] * (1.0f / D_) + 1e-6f);
    float o0 = g[t]       * d0 * rstd + bta[t];
    float o1 = g[t + 256] * d1 * rstd + bta[t + 256];
    float o2 = g[t + 512] * d2 * rstd + bta[t + 512];
    x[base + t]       = o0;
    x[base + t + 256] = o1;
    x[base + t + 512] = o2;
    xb[base + t]       = __float2bfloat16(o0);
    xb[base + t + 256] = __float2bfloat16(o1);
    xb[base + t + 512] = __float2bfloat16(o2);
}

// ----------------------------- mean pool over S ----------------------------
__global__ void pool_kernel(const float* __restrict__ x, float* __restrict__ pooled) {
    int idx = blockIdx.x * 256 + threadIdx.x;   // b*768 + d
    int b = idx / D_, d = idx % D_;
    float acc = 0.f;
    const float* p = x + (size_t)b * S_ * D_ + d;
    for (int s = 0; s < S_; s++) acc += p[(size_t)s * D_];
    pooled[idx] = acc * (1.0f / S_);
}

// ----------------------------- classifier head -----------------------------
__global__ void head_kernel(const float* __restrict__ pooled,
                            const float* __restrict__ wl,
                            const float* __restrict__ bl,
                            const float* __restrict__ wout,
                            const float* __restrict__ bout,
                            float* __restrict__ out)
{
    __shared__ float hb[32];
    int b = blockIdx.x, t = threadIdx.x;
    if (t < 32) {
        float z = bl[t];
        for (int d = 0; d < D_; d++) z += pooled[b * D_ + d] * wl[d * 32 + t];
        hb[t] = 0.5f * z * (1.0f + erff(z * 0.70710678118654752f));
    }
    __syncthreads();
    if (t == 0) {
        float z = bout[0];
        for (int j = 0; j < 32; j++) z += hb[j] * wout[j];
        out[b] = 1.0f / (1.0f + expf(-z));
    }
}

// ---------------------------------------------------------------------------
extern "C" void kernel_launch(void* const* d_in, const int* in_sizes, int n_in,
                              void* d_out, int out_size, void* d_ws, size_t ws_size,
                              hipStream_t stream)
{
    (void)in_sizes; (void)n_in; (void)out_size; (void)ws_size;
    const int*   tokens = (const int*)  d_in[0];
    const float* emb    = (const float*)d_in[1];
    const float* wq     = (const float*)d_in[2];
    const float* bq     = (const float*)d_in[3];
    const float* wk     = (const float*)d_in[4];
    const float* bk     = (const float*)d_in[5];
    const float* wv     = (const float*)d_in[6];
    const float* bv     = (const float*)d_in[7];
    const float* wo     = (const float*)d_in[8];
    const float* bo     = (const float*)d_in[9];
    const float* w1     = (const float*)d_in[10];
    const float* b1     = (const float*)d_in[11];
    const float* w2     = (const float*)d_in[12];
    const float* b2     = (const float*)d_in[13];
    const float* ln1g   = (const float*)d_in[14];
    const float* ln1b   = (const float*)d_in[15];
    const float* ln2g   = (const float*)d_in[16];
    const float* ln2b   = (const float*)d_in[17];
    const float* wl     = (const float*)d_in[18];
    const float* bl     = (const float*)d_in[19];
    const float* wout   = (const float*)d_in[20];
    const float* bout   = (const float*)d_in[21];
    float* out = (float*)d_out;

    char* ws = (char*)d_ws;
    size_t off = 0;
    auto alloc = [&](size_t n) -> void* {
        char* p = ws + off;
        off = (off + n + 255) & ~(size_t)255;
        return (void*)p;
    };
    const size_t XBYTES = (size_t)B_ * S_ * D_ * 4;        // 50.33 MB
    const size_t XBF    = XBYTES / 2;                      // 25.17 MB
    float*          pe     = (float*)alloc((size_t)S_ * D_ * 4);
    float*          x      = (float*)alloc(XBYTES);
    __hip_bfloat16* xb     = (__hip_bfloat16*)alloc(XBF);
    float*          qb     = (float*)alloc(XBYTES);        // fp32 GEMM out for add_ln
    char*           arena  = (char*)alloc(4 * XBF);        // 100.66 MB
    __hip_bfloat16* q_bf   = (__hip_bfloat16*)(arena + 0 * XBF);
    __hip_bfloat16* k_bf   = (__hip_bfloat16*)(arena + 1 * XBF);
    __hip_bfloat16* v_bf   = (__hip_bfloat16*)(arena + 2 * XBF);
    __hip_bfloat16* av_bf  = (__hip_bfloat16*)(arena + 3 * XBF);
    __hip_bfloat16* h_bf   = (__hip_bfloat16*)arena;       // [16384][3072] aliases qkv+av
    __hip_bfloat16* wT     = (__hip_bfloat16*)alloc((size_t)L_ * 7077888 * 2);
    float*          pooled = (float*)alloc((size_t)B_ * D_ * 4);
    // total ~285 MB

    const int M = B_ * S_;                                 // 16384
    const size_t DD = (size_t)D_ * D_;
    const size_t DF = (size_t)D_ * FF_;
    const size_t LSTRIDE = 4 * DD + 2 * DF;

    for (int l = 0; l < L_; l++) {
        __hip_bfloat16* wl_base = wT + (size_t)l * LSTRIDE;
        transpose_bf16<<<dim3(D_ / 32, D_ / 32), 256, 0, stream>>>(
            wq + l * DD, wl_base + 0 * DD, D_, D_);
        transpose_bf16<<<dim3(D_ / 32, D_ / 32), 256, 0, stream>>>(
            wk + l * DD, wl_base + 1 * DD, D_, D_);
        transpose_bf16<<<dim3(D_ / 32, D_ / 32), 256, 0, stream>>>(
            wv + l * DD, wl_base + 2 * DD, D_, D_);
        transpose_bf16<<<dim3(D_ / 32, D_ / 32), 256, 0, stream>>>(
            wo + l * DD, wl_base + 3 * DD, D_, D_);
        transpose_bf16<<<dim3(FF_ / 32, D_ / 32), 256, 0, stream>>>(
            w1 + l * DF, wl_base + 4 * DD, D_, FF_);
        transpose_bf16<<<dim3(D_ / 32, FF_ / 32), 256, 0, stream>>>(
            w2 + l * DF, wl_base + 4 * DD + DF, FF_, D_);
    }

    pe_kernel<<<(S_ * D_ + 255) / 256, 256, 0, stream>>>(pe);
    embed_kernel<<<M, 256, 0, stream>>>(tokens, emb, pe, x, xb);

    for (int l = 0; l < L_; l++) {
        __hip_bfloat16* wl_base = wT + (size_t)l * LSTRIDE;
        const ushort* wqT = (const ushort*)(wl_base + 0 * DD);
        const ushort* wkT = (const ushort*)(wl_base + 1 * DD);
        const ushort* wvT = (const ushort*)(wl_base + 2 * DD);
        const ushort* woT = (const ushort*)(wl_base + 3 * DD);
        const ushort* w1T = (const ushort*)(wl_base + 4 * DD);
        const ushort* w2T = (const ushort*)(wl_base + 4 * DD + DF);

        dim3 gdd(D_ / 128, M / 128);
        gemm_mfma<1,0><<<gdd, 256, 0, stream>>>(
            (const ushort*)xb, wqT, bq + l * D_, q_bf, M, D_, D_);
        gemm_mfma<1,0><<<gdd, 256, 0, stream>>>(
            (const ushort*)xb, wkT, bk + l * D_, k_bf, M, D_, D_);
        gemm_mfma<1,0><<<gdd, 256, 0, stream>>>(
            (const ushort*)xb, wvT, bv + l * D_, v_bf, M, D_, D_);

        attn_mfma<<<dim3(S_ / 128, H_, B_), 256, 0, stream>>>(
            (const ushort*)q_bf, (const ushort*)k_bf, (const ushort*)v_bf, av_bf);

        gemm_mfma<0,0><<<gdd, 256, 0, stream>>>(
            (const ushort*)av_bf, woT, bo + l * D_, qb, M, D_, D_);
        add_ln<<<M, 256, 0, stream>>>(x, xb, qb, ln1g + l * D_, ln1b + l * D_);

        gemm_mfma<1,1><<<dim3(FF_ / 128, M / 128), 256, 0, stream>>>(
            (const ushort*)xb, w1T, b1 + l * FF_, h_bf, M, FF_, D_);
        gemm_mfma<0,0><<<dim3(D_ / 128, M / 128), 256, 0, stream>>>(
            (const ushort*)h_bf, w2T, b2 + l * D_, qb, M, D_, FF_);
        add_ln<<<M, 256, 0, stream>>>(x, xb, qb, ln2g + l * D_, ln2b + l * D_);
    }

    pool_kernel<<<(B_ * D_) / 256, 256, 0, stream>>>(x, pooled);
    head_kernel<<<B_, 64, 0, stream>>>(pooled, wl, bl, wout, bout, out);
}

// Round 4
// 2353.792 us; speedup vs baseline: 7.4617x; 1.0673x over previous
//
#include <hip/hip_runtime.h>
#include <hip/hip_bf16.h>
#include <math.h>

// ---------------------------------------------------------------------------
// TextTransformer forward on MI355X — Round 4: fused QKV, attn LDS union,
// bf16 residuals, batched transposes.
// B=32 S=512 D=768 H=12 DH=64 FF=3072 L=4.
// GEMMs: m97 pattern (128x128, mfma 16x16x32_bf16, BK=32, global_load_lds 16).
// Attention: bf16 MFMA flash; sP aliases sQ (Q lives in regs after prologue);
//   scale folded into Q frags (exact bf16 exponent-3 trick).
// ---------------------------------------------------------------------------

#define B_  32
#define S_  512
#define D_  768
#define H_  12
#define DH_ 64
#define FF_ 3072
#define L_  4
#define QKVSTR 2304

typedef __attribute__((ext_vector_type(8))) short short8;   // 8 x bf16
typedef __attribute__((ext_vector_type(4))) float f32x4;

__device__ __forceinline__ void async16(const void* g, void* l) {
    __builtin_amdgcn_global_load_lds(
        (const __attribute__((address_space(1))) void*)g,
        (__attribute__((address_space(3))) void*)l, 16, 0, 0);
}

__device__ __forceinline__ ushort f2bf(float f) {
    __hip_bfloat16 h = __float2bfloat16(f);
    return __builtin_bit_cast(ushort, h);
}

// multiply a bf16 by 0.125 exactly: exponent -= 3 (flush tiny to signed 0)
__device__ __forceinline__ short8 scale8_eighth(short8 v) {
    short8 r;
#pragma unroll
    for (int e = 0; e < 8; e++) {
        ushort u = (ushort)v[e];
        ushort ex = u & 0x7f80;
        r[e] = (short)(ex > 0x0180 ? (ushort)(u - 0x0180) : (ushort)(u & 0x8000));
    }
    return r;
}

// ----------------------------- positional encoding -------------------------
__global__ void pe_kernel(float* __restrict__ pe) {
    int idx = blockIdx.x * 256 + threadIdx.x;
    if (idx >= S_ * D_) return;
    int s = idx / D_, j = idx % D_;
    double e = (2.0 * (double)(j >> 1)) / (double)D_;
    double denom = pow(10000.0, e);
    double ang = (double)s / denom;
    pe[idx] = (j & 1) ? (float)cos(ang) : (float)sin(ang);
}

// ----------------------------- embedding + PE ------------------------------
__global__ void embed_kernel(const int* __restrict__ tokens,
                             const float* __restrict__ emb,
                             const float* __restrict__ pe,
                             float* __restrict__ x,
                             __hip_bfloat16* __restrict__ xb) {
    int row = blockIdx.x;              // b*S + s
    int s = row & (S_ - 1);
    int tok = tokens[row];
    float scale = sqrtf((float)D_);
    for (int i = threadIdx.x; i < D_; i += 256) {
        float v = emb[(size_t)tok * D_ + i] * scale + pe[s * D_ + i];
        x[(size_t)row * D_ + i] = v;
        xb[(size_t)row * D_ + i] = __float2bfloat16(v);
    }
}

// ----------------------------- batched weight transpose fp32->bf16 ---------
// out[z][c][r] = (bf16) in[z][r][c].  Grid (C/32, R/32, L).
__global__ __launch_bounds__(256) void transpose_bf16_l(
    const float* __restrict__ in, __hip_bfloat16* __restrict__ out,
    int R, int C, size_t inL, size_t outL)
{
    __shared__ float tile[32][33];
    in  += (size_t)blockIdx.z * inL;
    out += (size_t)blockIdx.z * outL;
    int tx = threadIdx.x & 31, ty = threadIdx.x >> 5;   // 32 x 8
    int c0 = blockIdx.x * 32, r0 = blockIdx.y * 32;
#pragma unroll
    for (int d = 0; d < 32; d += 8)
        tile[ty + d][tx] = in[(size_t)(r0 + ty + d) * C + c0 + tx];
    __syncthreads();
#pragma unroll
    for (int d = 0; d < 32; d += 8)
        out[(size_t)(c0 + ty + d) * R + r0 + tx] = __float2bfloat16(tile[tx][ty + d]);
}

// ----------------------------- qkv bias concat -----------------------------
__global__ void biascat(const float* __restrict__ bq, const float* __restrict__ bk,
                        const float* __restrict__ bv, float* __restrict__ o) {
    int i = blockIdx.x * 256 + threadIdx.x;          // [L_*2304)
    int ll = i / QKVSTR, j = i % QKVSTR;
    o[i] = j < 768 ? bq[ll * 768 + j]
         : j < 1536 ? bk[ll * 768 + j - 768]
                    : bv[ll * 768 + j - 1536];
}

// ----------------------------- bf16 MFMA GEMM ------------------------------
// C[M,N] = A[M,K] @ Bt[N,K]^T + bias[N].  M%128==0, N%128==0, K%32==0.
template<int OUT_BF16, int RELU>
__global__ __launch_bounds__(256) void gemm_mfma(
    const ushort* __restrict__ A,   // bf16 [M][K]
    const ushort* __restrict__ Bt,  // bf16 [N][K]
    const float* __restrict__ bias, // fp32 [N]
    void* __restrict__ Cout,        // fp32 or bf16 [M][N]
    int M, int N, int K)
{
    __shared__ alignas(16) ushort sA[128 * 32];
    __shared__ alignas(16) ushort sB[128 * 32];
    int t = threadIdx.x;
    int n0 = blockIdx.x * 128, m0 = blockIdx.y * 128;
    int l = t & 63, w = t >> 6;
    int wm = (w >> 1) * 64, wn = (w & 1) * 64;

    int idx0 = t * 8;
    int row0 = idx0 >> 5, col0 = idx0 & 31;
    int idx1 = idx0 + 2048;
    int row1 = idx1 >> 5, col1 = idx1 & 31;
    const ushort* Ab = A + (size_t)m0 * K;
    const ushort* Bb = Bt + (size_t)n0 * K;

    int lm = l & 15, lq = l >> 4;
    int aoff = (wm + lm) * 32 + lq * 8;
    int boff = (wn + lm) * 32 + lq * 8;

    f32x4 acc[4][4];
#pragma unroll
    for (int i = 0; i < 4; i++)
#pragma unroll
        for (int j = 0; j < 4; j++) acc[i][j] = (f32x4){0.f, 0.f, 0.f, 0.f};

    for (int k0 = 0; k0 < K; k0 += 32) {
        __syncthreads();
        async16(Ab + (size_t)row0 * K + k0 + col0, &sA[idx0]);
        async16(Ab + (size_t)row1 * K + k0 + col1, &sA[idx1]);
        async16(Bb + (size_t)row0 * K + k0 + col0, &sB[idx0]);
        async16(Bb + (size_t)row1 * K + k0 + col1, &sB[idx1]);
        __syncthreads();
        short8 a[4], b[4];
#pragma unroll
        for (int i = 0; i < 4; i++) a[i] = *(const short8*)&sA[aoff + i * 512];
#pragma unroll
        for (int j = 0; j < 4; j++) b[j] = *(const short8*)&sB[boff + j * 512];
#pragma unroll
        for (int i = 0; i < 4; i++)
#pragma unroll
            for (int j = 0; j < 4; j++)
                acc[i][j] = __builtin_amdgcn_mfma_f32_16x16x32_bf16(
                    a[i], b[j], acc[i][j], 0, 0, 0);
    }

    int rb = m0 + wm + lq * 4;
    int cb = n0 + wn + lm;
#pragma unroll
    for (int j = 0; j < 4; j++) {
        int c = cb + j * 16;
        float bs = bias[c];
#pragma unroll
        for (int i = 0; i < 4; i++) {
#pragma unroll
            for (int r = 0; r < 4; r++) {
                float v = acc[i][j][r] + bs;
                if (RELU) v = fmaxf(v, 0.f);
                size_t o = (size_t)(rb + i * 16 + r) * N + c;
                if (OUT_BF16) ((__hip_bfloat16*)Cout)[o] = __float2bfloat16(v);
                else          ((float*)Cout)[o] = v;
            }
        }
    }
}

// ----------------------------- MFMA flash attention ------------------------
// Block: (qt of 128 rows, h, b); 4 waves; wave w owns q-rows wm=w*32..+32.
// qkv is the fused [B*S][2304] buffer: q at col 0, k at 768, v at 1536.
// sP aliases sQ (Q is register-resident after the prologue). LDS ~36.9 KB.
#define PSTR 72
__global__ __launch_bounds__(256) void attn_mfma(
    const ushort* __restrict__ qkv,
    __hip_bfloat16* __restrict__ av)
{
    __shared__ alignas(16) ushort sQP[128 * PSTR];   // Q tile, then P (per-wave)
    __shared__ alignas(16) ushort sK[64 * PSTR];
    __shared__ alignas(16) ushort sVt[64 * PSTR];    // Vt[d][s]

    int t = threadIdx.x;
    int qt = blockIdx.x, h = blockIdx.y, b = blockIdx.z;
    int w = t >> 6, l = t & 63;
    int lm = l & 15, lq = l >> 4;
    int wm = w * 32;

    const ushort* qbase = qkv + (size_t)(b * S_ + qt * 128) * QKVSTR + h * DH_;
    const ushort* kbase = qkv + (size_t)b * S_ * QKVSTR + 768 + h * DH_;
    const ushort* vbase = qkv + (size_t)b * S_ * QKVSTR + 1536 + h * DH_;

    // stage Q tile [128][64]
    {
        int r = t >> 1, c0 = (t & 1) * 32;
        const ushort* src = qbase + (size_t)r * QKVSTR + c0;
        ushort* dst = &sQP[r * PSTR + c0];
        *(uint4*)(dst + 0)  = *(const uint4*)(src + 0);
        *(uint4*)(dst + 8)  = *(const uint4*)(src + 8);
        *(uint4*)(dst + 16) = *(const uint4*)(src + 16);
        *(uint4*)(dst + 24) = *(const uint4*)(src + 24);
    }
    __syncthreads();
    short8 qf[2][2];
#pragma unroll
    for (int i = 0; i < 2; i++)
#pragma unroll
        for (int ks = 0; ks < 2; ks++)
            qf[i][ks] = scale8_eighth(
                *(const short8*)&sQP[(wm + i * 16 + lm) * PSTR + ks * 32 + lq * 8]);

    ushort* sPw = &sQP[(size_t)wm * PSTR];           // wave-local P region

    f32x4 accO[2][4];
    float mrun[2][4], lrun[2][4];
#pragma unroll
    for (int i = 0; i < 2; i++)
#pragma unroll
        for (int j = 0; j < 4; j++) accO[i][j] = (f32x4){0.f, 0.f, 0.f, 0.f};
#pragma unroll
    for (int i = 0; i < 2; i++)
#pragma unroll
        for (int r = 0; r < 4; r++) { mrun[i][r] = -1e30f; lrun[i][r] = 0.f; }

    for (int kt = 0; kt < S_ / 64; kt++) {
        __syncthreads();   // prior reads of sK/sVt done; first iter: qf loads done
        {
            int r = t >> 2, c0 = (t & 3) * 16;
            const ushort* ksrc = kbase + (size_t)(kt * 64 + r) * QKVSTR + c0;
            ushort* kdst = &sK[r * PSTR + c0];
            *(uint4*)(kdst + 0) = *(const uint4*)(ksrc + 0);
            *(uint4*)(kdst + 8) = *(const uint4*)(ksrc + 8);
            const ushort* vsrc = vbase + (size_t)(kt * 64 + r) * QKVSTR + c0;
            ushort vv[16];
            *(uint4*)&vv[0] = *(const uint4*)(vsrc + 0);
            *(uint4*)&vv[8] = *(const uint4*)(vsrc + 8);
#pragma unroll
            for (int j = 0; j < 16; j++) sVt[(c0 + j) * PSTR + r] = vv[j];
        }
        __syncthreads();

        // S = (Q/8) K^T
        f32x4 accS[2][4];
#pragma unroll
        for (int i = 0; i < 2; i++)
#pragma unroll
            for (int j = 0; j < 4; j++) accS[i][j] = (f32x4){0.f, 0.f, 0.f, 0.f};
#pragma unroll
        for (int ks = 0; ks < 2; ks++) {
#pragma unroll
            for (int j = 0; j < 4; j++) {
                short8 kf = *(const short8*)&sK[(j * 16 + lm) * PSTR + ks * 32 + lq * 8];
#pragma unroll
                for (int i = 0; i < 2; i++)
                    accS[i][j] = __builtin_amdgcn_mfma_f32_16x16x32_bf16(
                        qf[i][ks], kf, accS[i][j], 0, 0, 0);
            }
        }

        // online softmax
        float rmax[2][4];
#pragma unroll
        for (int i = 0; i < 2; i++)
#pragma unroll
            for (int r = 0; r < 4; r++)
                rmax[i][r] = fmaxf(fmaxf(accS[i][0][r], accS[i][1][r]),
                                   fmaxf(accS[i][2][r], accS[i][3][r]));
#pragma unroll
        for (int d = 1; d < 16; d <<= 1)
#pragma unroll
            for (int i = 0; i < 2; i++)
#pragma unroll
                for (int r = 0; r < 4; r++)
                    rmax[i][r] = fmaxf(rmax[i][r], __shfl_xor(rmax[i][r], d));

        float alpha[2][4];
#pragma unroll
        for (int i = 0; i < 2; i++)
#pragma unroll
            for (int r = 0; r < 4; r++) {
                float mn = fmaxf(mrun[i][r], rmax[i][r]);
                alpha[i][r] = __expf(mrun[i][r] - mn);
                mrun[i][r] = mn;
            }
        float rsum[2][4];
#pragma unroll
        for (int i = 0; i < 2; i++)
#pragma unroll
            for (int r = 0; r < 4; r++) rsum[i][r] = 0.f;
#pragma unroll
        for (int i = 0; i < 2; i++)
#pragma unroll
            for (int j = 0; j < 4; j++)
#pragma unroll
                for (int r = 0; r < 4; r++) {
                    float p = __expf(accS[i][j][r] - mrun[i][r]);
                    accS[i][j][r] = p;
                    rsum[i][r] += p;
                }
#pragma unroll
        for (int d = 1; d < 16; d <<= 1)
#pragma unroll
            for (int i = 0; i < 2; i++)
#pragma unroll
                for (int r = 0; r < 4; r++)
                    rsum[i][r] += __shfl_xor(rsum[i][r], d);
#pragma unroll
        for (int i = 0; i < 2; i++)
#pragma unroll
            for (int r = 0; r < 4; r++)
                lrun[i][r] = lrun[i][r] * alpha[i][r] + rsum[i][r];

        // rescale O
#pragma unroll
        for (int i = 0; i < 2; i++)
#pragma unroll
            for (int j = 0; j < 4; j++)
#pragma unroll
                for (int r = 0; r < 4; r++) accO[i][j][r] *= alpha[i][r];

        // P -> wave-local LDS (C-layout -> A-layout round trip; no barrier)
#pragma unroll
        for (int i = 0; i < 2; i++)
#pragma unroll
            for (int j = 0; j < 4; j++)
#pragma unroll
                for (int r = 0; r < 4; r++)
                    sPw[(i * 16 + lq * 4 + r) * PSTR + j * 16 + lm] =
                        f2bf(accS[i][j][r]);

        // O += P V   (B-frags from Vt[d][s])
#pragma unroll
        for (int ks = 0; ks < 2; ks++) {
            short8 pf[2];
#pragma unroll
            for (int i = 0; i < 2; i++)
                pf[i] = *(const short8*)&sPw[(i * 16 + lm) * PSTR + ks * 32 + lq * 8];
#pragma unroll
            for (int j = 0; j < 4; j++) {
                short8 vf = *(const short8*)&sVt[(j * 16 + lm) * PSTR + ks * 32 + lq * 8];
#pragma unroll
                for (int i = 0; i < 2; i++)
                    accO[i][j] = __builtin_amdgcn_mfma_f32_16x16x32_bf16(
                        pf[i], vf, accO[i][j], 0, 0, 0);
            }
        }
    }

    // epilogue
    float invl[2][4];
#pragma unroll
    for (int i = 0; i < 2; i++)
#pragma unroll
        for (int r = 0; r < 4; r++) invl[i][r] = 1.0f / lrun[i][r];
#pragma unroll
    for (int i = 0; i < 2; i++)
#pragma unroll
        for (int j = 0; j < 4; j++)
#pragma unroll
            for (int r = 0; r < 4; r++) {
                int row = qt * 128 + wm + i * 16 + lq * 4 + r;
                int col = h * DH_ + j * 16 + lm;
                av[(size_t)(b * S_ + row) * D_ + col] =
                    __float2bfloat16(accO[i][j][r] * invl[i][r]);
            }
}

// ----------------------------- residual + layernorm ------------------------
__global__ __launch_bounds__(256) void add_ln(float* __restrict__ x,
    __hip_bfloat16* __restrict__ xb,
    const __hip_bfloat16* __restrict__ r, const float* __restrict__ g,
    const float* __restrict__ bta)
{
    __shared__ float sred[256];
    int row = blockIdx.x, t = threadIdx.x;
    size_t base = (size_t)row * D_;
    float v0 = x[base + t]       + __bfloat162float(r[base + t]);
    float v1 = x[base + t + 256] + __bfloat162float(r[base + t + 256]);
    float v2 = x[base + t + 512] + __bfloat162float(r[base + t + 512]);
    sred[t] = v0 + v1 + v2;
    __syncthreads();
    for (int o = 128; o > 0; o >>= 1) { if (t < o) sred[t] += sred[t + o]; __syncthreads(); }
    float mean = sred[0] * (1.0f / D_);
    __syncthreads();
    float d0 = v0 - mean, d1 = v1 - mean, d2 = v2 - mean;
    sred[t] = d0 * d0 + d1 * d1 + d2 * d2;
    __syncthreads();
    for (int o = 128; o > 0; o >>= 1) { if (t < o) sred[t] += sred[t + o]; __syncthreads(); }
    float rstd = rsqrtf(sred[0] * (1.0f / D_) + 1e-6f);
    float o0 = g[t]       * d0 * rstd + bta[t];
    float o1 = g[t + 256] * d1 * rstd + bta[t + 256];
    float o2 = g[t + 512] * d2 * rstd + bta[t + 512];
    x[base + t]       = o0;
    x[base + t + 256] = o1;
    x[base + t + 512] = o2;
    xb[base + t]       = __float2bfloat16(o0);
    xb[base + t + 256] = __float2bfloat16(o1);
    xb[base + t + 512] = __float2bfloat16(o2);
}

// ----------------------------- mean pool over S ----------------------------
__global__ void pool_kernel(const float* __restrict__ x, float* __restrict__ pooled) {
    int idx = blockIdx.x * 256 + threadIdx.x;   // b*768 + d
    int b = idx / D_, d = idx % D_;
    float acc = 0.f;
    const float* p = x + (size_t)b * S_ * D_ + d;
    for (int s = 0; s < S_; s++) acc += p[(size_t)s * D_];
    pooled[idx] = acc * (1.0f / S_);
}

// ----------------------------- classifier head -----------------------------
__global__ void head_kernel(const float* __restrict__ pooled,
                            const float* __restrict__ wl,
                            const float* __restrict__ bl,
                            const float* __restrict__ wout,
                            const float* __restrict__ bout,
                            float* __restrict__ out)
{
    __shared__ float hb[32];
    int b = blockIdx.x, t = threadIdx.x;
    if (t < 32) {
        float z = bl[t];
        for (int d = 0; d < D_; d++) z += pooled[b * D_ + d] * wl[d * 32 + t];
        hb[t] = 0.5f * z * (1.0f + erff(z * 0.70710678118654752f));
    }
    __syncthreads();
    if (t == 0) {
        float z = bout[0];
        for (int j = 0; j < 32; j++) z += hb[j] * wout[j];
        out[b] = 1.0f / (1.0f + expf(-z));
    }
}

// ---------------------------------------------------------------------------
extern "C" void kernel_launch(void* const* d_in, const int* in_sizes, int n_in,
                              void* d_out, int out_size, void* d_ws, size_t ws_size,
                              hipStream_t stream)
{
    (void)in_sizes; (void)n_in; (void)out_size; (void)ws_size;
    const int*   tokens = (const int*)  d_in[0];
    const float* emb    = (const float*)d_in[1];
    const float* wq     = (const float*)d_in[2];
    const float* bq     = (const float*)d_in[3];
    const float* wk     = (const float*)d_in[4];
    const float* bk     = (const float*)d_in[5];
    const float* wv     = (const float*)d_in[6];
    const float* bv     = (const float*)d_in[7];
    const float* wo     = (const float*)d_in[8];
    const float* bo     = (const float*)d_in[9];
    const float* w1     = (const float*)d_in[10];
    const float* b1     = (const float*)d_in[11];
    const float* w2     = (const float*)d_in[12];
    const float* b2     = (const float*)d_in[13];
    const float* ln1g   = (const float*)d_in[14];
    const float* ln1b   = (const float*)d_in[15];
    const float* ln2g   = (const float*)d_in[16];
    const float* ln2b   = (const float*)d_in[17];
    const float* wl     = (const float*)d_in[18];
    const float* bl     = (const float*)d_in[19];
    const float* wout   = (const float*)d_in[20];
    const float* bout   = (const float*)d_in[21];
    float* out = (float*)d_out;

    char* ws = (char*)d_ws;
    size_t off = 0;
    auto alloc = [&](size_t n) -> void* {
        char* p = ws + off;
        off = (off + n + 255) & ~(size_t)255;
        return (void*)p;
    };
    const size_t XBYTES = (size_t)B_ * S_ * D_ * 4;        // 50.33 MB
    const size_t XBF    = XBYTES / 2;                      // 25.17 MB
    float*          pe     = (float*)alloc((size_t)S_ * D_ * 4);
    float*          x      = (float*)alloc(XBYTES);
    __hip_bfloat16* xb     = (__hip_bfloat16*)alloc(XBF);
    __hip_bfloat16* r_bf   = (__hip_bfloat16*)alloc(XBF);  // residual branch
    char*           arena  = (char*)alloc(4 * XBF);        // 100.66 MB
    __hip_bfloat16* qkv_bf = (__hip_bfloat16*)arena;       // [M][2304]
    __hip_bfloat16* av_bf  = (__hip_bfloat16*)(arena + 3 * XBF);
    __hip_bfloat16* h_bf   = (__hip_bfloat16*)arena;       // [M][3072] aliases qkv+av
    __hip_bfloat16* wT     = (__hip_bfloat16*)alloc((size_t)L_ * 7077888 * 2);
    float*          qkvbias= (float*)alloc((size_t)L_ * QKVSTR * 4);
    float*          pooled = (float*)alloc((size_t)B_ * D_ * 4);
    // total ~260 MB

    const int M = B_ * S_;                                 // 16384
    const size_t DD = (size_t)D_ * D_;
    const size_t DF = (size_t)D_ * FF_;
    const size_t LSTRIDE = 4 * DD + 2 * DF;

    // weights: per layer [qkvT(3*DD) | woT(DD) | w1T(DF) | w2T(DF)]
    transpose_bf16_l<<<dim3(D_ / 32, D_ / 32, L_), 256, 0, stream>>>(
        wq, wT + 0 * DD, D_, D_, DD, LSTRIDE);
    transpose_bf16_l<<<dim3(D_ / 32, D_ / 32, L_), 256, 0, stream>>>(
        wk, wT + 1 * DD, D_, D_, DD, LSTRIDE);
    transpose_bf16_l<<<dim3(D_ / 32, D_ / 32, L_), 256, 0, stream>>>(
        wv, wT + 2 * DD, D_, D_, DD, LSTRIDE);
    transpose_bf16_l<<<dim3(D_ / 32, D_ / 32, L_), 256, 0, stream>>>(
        wo, wT + 3 * DD, D_, D_, DD, LSTRIDE);
    transpose_bf16_l<<<dim3(FF_ / 32, D_ / 32, L_), 256, 0, stream>>>(
        w1, wT + 4 * DD, D_, FF_, DF, LSTRIDE);
    transpose_bf16_l<<<dim3(D_ / 32, FF_ / 32, L_), 256, 0, stream>>>(
        w2, wT + 4 * DD + DF, FF_, D_, DF, LSTRIDE);
    biascat<<<(L_ * QKVSTR) / 256, 256, 0, stream>>>(bq, bk, bv, qkvbias);

    pe_kernel<<<(S_ * D_ + 255) / 256, 256, 0, stream>>>(pe);
    embed_kernel<<<M, 256, 0, stream>>>(tokens, emb, pe, x, xb);

    for (int l = 0; l < L_; l++) {
        __hip_bfloat16* wl_base = wT + (size_t)l * LSTRIDE;
        const ushort* qkvT = (const ushort*)(wl_base + 0 * DD);
        const ushort* woT  = (const ushort*)(wl_base + 3 * DD);
        const ushort* w1T  = (const ushort*)(wl_base + 4 * DD);
        const ushort* w2T  = (const ushort*)(wl_base + 4 * DD + DF);

        gemm_mfma<1,0><<<dim3(QKVSTR / 128, M / 128), 256, 0, stream>>>(
            (const ushort*)xb, qkvT, qkvbias + (size_t)l * QKVSTR, qkv_bf,
            M, QKVSTR, D_);

        attn_mfma<<<dim3(S_ / 128, H_, B_), 256, 0, stream>>>(
            (const ushort*)qkv_bf, av_bf);

        gemm_mfma<1,0><<<dim3(D_ / 128, M / 128), 256, 0, stream>>>(
            (const ushort*)av_bf, woT, bo + l * D_, r_bf, M, D_, D_);
        add_ln<<<M, 256, 0, stream>>>(x, xb, r_bf, ln1g + l * D_, ln1b + l * D_);

        gemm_mfma<1,1><<<dim3(FF_ / 128, M / 128), 256, 0, stream>>>(
            (const ushort*)xb, w1T, b1 + l * FF_, h_bf, M, FF_, D_);
        gemm_mfma<1,0><<<dim3(D_ / 128, M / 128), 256, 0, stream>>>(
            (const ushort*)h_bf, w2T, b2 + l * D_, r_bf, M, D_, FF_);
        add_ln<<<M, 256, 0, stream>>>(x, xb, r_bf, ln2g + l * D_, ln2b + l * D_);
    }

    pool_kernel<<<(B_ * D_) / 256, 256, 0, stream>>>(x, pooled);
    head_kernel<<<B_, 64, 0, stream>>>(pooled, wl, bl, wout, bout, out);
}